// Round 1
// baseline (342.845 us; speedup 1.0000x reference)
//
#include <hip/hip_runtime.h>
#include <stdint.h>

#define N_ROWS 32768
#define D_DIM  1024
#define C_TREES 64
#define K_LEAF 16
#define M_OUT  1024

// ---------------- Kernel A: transpose lut (M, C*K=1024) -> lutT (C*K, M) ----------------
__global__ __launch_bounds__(256) void k_transpose(const float* __restrict__ lut,
                                                   float* __restrict__ lutT) {
    __shared__ float tile[32][33];
    int bx = blockIdx.x;          // tile along ck (source col)
    int by = blockIdx.y;          // tile along m  (source row)
    int tx = threadIdx.x;         // 0..31
    int ty = threadIdx.y;         // 0..7
    int src_col = bx * 32 + tx;
#pragma unroll
    for (int i = 0; i < 4; ++i) {
        int src_row = by * 32 + ty + i * 8;
        tile[ty + i * 8][tx] = lut[(size_t)src_row * 1024 + src_col];
    }
    __syncthreads();
    int dst_col = by * 32 + tx;   // m
#pragma unroll
    for (int i = 0; i < 4; ++i) {
        int dst_row = bx * 32 + ty + i * 8;   // ck
        lutT[(size_t)dst_row * 1024 + dst_col] = tile[tx][ty + i * 8];
    }
}

// ---------------- Kernel B: encode leaf indices ----------------
// leaf[c][n] u8, c-major so k_accum reads coalesced per c.
__global__ __launch_bounds__(256) void k_encode(const float* __restrict__ in,
                                                const int* __restrict__ dims,
                                                const float* __restrict__ th,
                                                uint8_t* __restrict__ leaf) {
    __shared__ float rows[8][1028];   // +4 pad: r-groups land on distinct banks
    __shared__ float th_s[960];
    __shared__ int   dims_s[256];
    int t = threadIdx.x;
    dims_s[t] = dims[t];
    for (int i = t; i < 960; i += 256) th_s[i] = th[i];
    int n0 = blockIdx.x * 8;
    const float4* in4 = (const float4*)(in + (size_t)n0 * 1024);
#pragma unroll
    for (int i = 0; i < 8; ++i) {
        ((float4*)&rows[i][0])[t] = in4[i * 256 + t];
    }
    __syncthreads();
    // 512 tasks = 64 c x 8 r ; lanes within a wave share c in groups of 8
#pragma unroll
    for (int i = 0; i < 2; ++i) {
        int id = i * 256 + t;
        int c = id >> 3;        // 0..63
        int r = id & 7;         // 0..7
        int node = 0;
        const float* trow = &rows[r][0];
#pragma unroll
        for (int lvl = 0; lvl < 4; ++lvl) {
            float x   = trow[dims_s[c * 4 + lvl]];
            float thv = th_s[c * 15 + node];
            node = 2 * node + 1 + ((x > thv) ? 1 : 0);
        }
        leaf[(size_t)c * N_ROWS + n0 + r] = (uint8_t)(node - 15);
    }
}

// ---------------- Kernel C: accumulate out[n,m] = sum_c lutT[c*16+leaf][m] ----------------
// Block: 512 threads, tile 128n x 128m. Per c: stage 16x128 f32 slice (8KB),
// double-buffered via global_load_lds(16B), ONE barrier per c.
__global__ __launch_bounds__(512) void k_accum(const float* __restrict__ lutT,
                                               const uint8_t* __restrict__ leaf,
                                               float* __restrict__ out) {
    __shared__ float4 sl[2][16][32];   // [buf][k][m-chunk], 16KB

    int t     = threadIdx.x;
    int mlane = t & 31;                // float4 column within m-tile
    int ngrp  = t >> 5;                // 0..15 (8 n each)
    int wave  = t >> 6;                // 0..7
    int lane  = t & 63;
    int srow  = 2 * wave + (lane >> 5);   // staging row 0..15
    int schunk = lane & 31;               // staging chunk 0..31

    int m0 = blockIdx.x * 128;
    int n0 = blockIdx.y * 128;

    const float4* lutT4 = (const float4*)lutT;

    auto stage = [&](int buf, int c) {
        const float4* src = lutT4 + ((size_t)(c * 16 + srow) * 256) + (m0 >> 2) + schunk;
        __builtin_amdgcn_global_load_lds((const __attribute__((address_space(1))) void*)src,
                                         (__attribute__((address_space(3))) void*)&sl[buf][2 * wave][0],
                                         16, 0, 0);
    };

    float4 acc[8];
#pragma unroll
    for (int j = 0; j < 8; ++j) acc[j] = make_float4(0.f, 0.f, 0.f, 0.f);

    const uint8_t* lp = leaf + n0 + ngrp * 8;
    uint64_t lv = *(const uint64_t*)lp;          // leaves for c=0
    stage(0, 0);

#pragma unroll 2
    for (int c = 0; c < 64; ++c) {
        __syncthreads();                         // stage(c) drained (vmcnt0 before barrier)
        if (c < 63) stage((c + 1) & 1, c + 1);   // next slice in flight across compute
        uint64_t lv_next = (c < 63) ? *(const uint64_t*)(lp + (size_t)(c + 1) * N_ROWS) : 0ull;
        int buf = c & 1;
#pragma unroll
        for (int j = 0; j < 8; ++j) {
            int k = (int)((lv >> (8 * j)) & 15);
            float4 v = sl[buf][k][mlane];
            acc[j].x += v.x; acc[j].y += v.y; acc[j].z += v.z; acc[j].w += v.w;
        }
        lv = lv_next;
    }

    float4* out4 = (float4*)out;
#pragma unroll
    for (int j = 0; j < 8; ++j) {
        int n = n0 + ngrp * 8 + j;
        out4[(size_t)n * 256 + (m0 >> 2) + mlane] = acc[j];
    }
}

extern "C" void kernel_launch(void* const* d_in, const int* in_sizes, int n_in,
                              void* d_out, int out_size, void* d_ws, size_t ws_size,
                              hipStream_t stream) {
    const float* inputMatrix = (const float*)d_in[0];
    const int*   dims        = (const int*)d_in[1];
    const float* thresholds  = (const float*)d_in[2];
    const float* lut         = (const float*)d_in[3];
    // d_in[4] selection_matrix, d_in[5] tree_des_mat: structure is hardcoded.
    float* out = (float*)d_out;

    float*   lutT = (float*)d_ws;                                  // 4 MB
    uint8_t* leaf = (uint8_t*)d_ws + (size_t)4 * 1024 * 1024;      // 2 MB

    k_transpose<<<dim3(32, 32), dim3(32, 8), 0, stream>>>(lut, lutT);
    k_encode<<<N_ROWS / 8, 256, 0, stream>>>(inputMatrix, dims, thresholds, leaf);
    k_accum<<<dim3(M_OUT / 128, N_ROWS / 128), 512, 0, stream>>>(lutT, leaf, out);
}